// Round 11
// baseline (281.892 us; speedup 1.0000x reference)
//
#include <hip/hip_runtime.h>
#include <hip/hip_bf16.h>

#define B_  4
#define S_  2048
#define E_  1024
#define H_  16
#define DH_ 64
#define M_  (B_*S_)    // 8192 rows
#define HD_ (H_*DH_)   // 1024

typedef unsigned short u16;
typedef __attribute__((ext_vector_type(8))) __bf16 bf16x8;
typedef __attribute__((ext_vector_type(4))) __bf16 bf16x4;
typedef __attribute__((ext_vector_type(4))) float  f32x4;

#if __has_builtin(__builtin_amdgcn_exp2f)
#define EXP2F __builtin_amdgcn_exp2f
#else
#define EXP2F __builtin_exp2f
#endif

// softmax scale folded into Q at QKV epilogue: 1/sqrt(64) * log2(e)
#define QSCALE 0.18033688011112042f

// ---- async global->LDS, 16B per lane ----
__device__ __forceinline__ void g2l16(const void* g, void* l) {
  __builtin_amdgcn_global_load_lds(
      (const __attribute__((address_space(1))) void*)g,
      (__attribute__((address_space(3))) void*)l, 16, 0, 0);
}

// RNE float -> bf16 bits (scalar path, used in prep only)
__device__ __forceinline__ u16 f2bf(float f) {
  union { float f; unsigned u; } v; v.f = f;
  unsigned r = v.u + 0x7FFFu + ((v.u >> 16) & 1u);
  return (u16)(r >> 16);
}

// ---------------- fused prep: cvt_x | pack_wqkv | pack_wo ----------------
__global__ __launch_bounds__(256) void prep_kernel(
    const float* __restrict__ x, const float* __restrict__ Wq,
    const float* __restrict__ Wk, const float* __restrict__ Wv,
    const float* __restrict__ Wo,
    u16* __restrict__ xb, u16* __restrict__ wqkvT, u16* __restrict__ woT) {
  __shared__ u16 tile[64][66];
  const int blk = blockIdx.x, tid = threadIdx.x;
  if (blk < 8192) {
    int i = blk * 256 + tid;
    float4 v = ((const float4*)x)[i];
    ushort4 o;
    o.x = f2bf(v.x); o.y = f2bf(v.y); o.z = f2bf(v.z); o.w = f2bf(v.w);
    ((ushort4*)xb)[i] = o;
  } else if (blk < 8960) {
    int b2 = blk - 8192;
    int p = b2 >> 8, h = (b2 >> 4) & 15, e0 = (b2 & 15) * 64;
    const float* src = (p == 0 ? Wq : (p == 1 ? Wk : Wv)) + h * (E_ * DH_);
#pragma unroll
    for (int r = 0; r < 16; ++r) {
      int idx = r * 256 + tid;
      int el = idx >> 6, d = idx & 63;
      tile[el][d] = f2bf(src[(e0 + el) * DH_ + d]);
    }
    __syncthreads();
    u16* dst = wqkvT + (p * HD_ + h * DH_) * E_;
#pragma unroll
    for (int r = 0; r < 16; ++r) {
      int idx = r * 256 + tid;
      int d = idx >> 6, el = idx & 63;
      dst[d * E_ + e0 + el] = tile[el][d];
    }
  } else {
    int b3 = blk - 8960;
    int c0 = (b3 >> 4) * 64, e0 = (b3 & 15) * 64;
#pragma unroll
    for (int r = 0; r < 16; ++r) {
      int idx = r * 256 + tid;
      int cl = idx >> 6, el = idx & 63;
      tile[cl][el] = f2bf(Wo[(c0 + cl) * E_ + e0 + el]);
    }
    __syncthreads();
#pragma unroll
    for (int r = 0; r < 16; ++r) {
      int idx = r * 256 + tid;
      int er = idx >> 6, cl = idx & 63;
      woT[(e0 + er) * HD_ + c0 + cl] = tile[cl][er];
    }
  }
}

// ---------------- GEMM (QKV): faithful 8-phase 256x256 template port ----------
// C[M][3072] = xb[M][1024] * wqkvT[3072][1024]^T.
// BM=BN=256, BK=64, 512 thr = 8 waves (2M x 4N), per-wave C = 128x64,
// acc[8][4]. LDS 128 KiB = 2 dbuf x (A 32KB + B 32KB).
// Per K-tile: 4 quadrant-phases x 16 MFMA; reads/phase = 12,4,8,0 via
// register-subtile reuse (template pattern). Phase 4 stages tile t+2 into
// buf(t) — SAFE because buf(t)'s last ds_read is in phase 3 (all waves,
// barrier-synced), with a "" memory clobber pinning reads above the issue.
// Tile boundary: counted s_waitcnt vmcnt(8) (= next tile's 8 loads; NEVER 0
// in steady state, T4) + barrier. setprio(1) around each MFMA cluster (T5).
// Grid 384 = 8 XCD x 48, bijective swizzle. 1 block/CU, 2 dispatch rounds.
// R3 lesson: the SIMPLIFIED 2-phase graft measured == m97 baseline; this is
// the full template interleave, which is where m218/m248 say the gain lives.
__global__ __launch_bounds__(512, 2) void gemm_qkv_kernel(
    const u16* __restrict__ A, const u16* __restrict__ Bt,
    const float* __restrict__ b0, const float* __restrict__ b1,
    const float* __restrict__ b2,
    u16* __restrict__ oQ, u16* __restrict__ oK, u16* __restrict__ oV) {
  constexpr int K = 1024;
  __shared__ __align__(16) u16 smem[65536];   // 128 KiB
  const int tid = threadIdx.x;
  const int lane = tid & 63, wv = tid >> 6;
  const int wr = wv >> 2, wc = wv & 3;        // 2 x 4 wave grid
  const int q4 = lane >> 4, lm = lane & 15;

  // XCD-bijective swizzle: 384 blocks, 48 per XCD
  const int bid = blockIdx.x;
  const int wg = (bid & 7) * 48 + (bid >> 3);
  const int tileN = (wg % 12) * 256;
  const int tileM = (wg / 12) * 256;

  // staging: 4 issues per operand per K-tile; issue p covers rows p*64..p*64+63
  const int sr = tid >> 3;
  const int swz = ((tid & 7) ^ (sr & 7)) * 8;
  const u16* gA = A + (size_t)(tileM + sr) * K + swz;
  const u16* gB = Bt + (size_t)(tileN + sr) * K + swz;

#define STG(t) do {                                                    \
    u16* dA = smem + ((t) & 1) * 32768;                                \
    u16* dB = dA + 16384;                                              \
    const u16* sA = gA + (t) * 64;                                     \
    const u16* sB = gB + (t) * 64;                                     \
    _Pragma("unroll")                                                  \
    for (int p = 0; p < 4; ++p) {                                      \
      g2l16(sA + (size_t)p * 64 * K, dA + p * 4096 + tid * 8);         \
      g2l16(sB + (size_t)p * 64 * K, dB + p * 4096 + tid * 8);         \
    }                                                                  \
  } while (0)

  // fragment offsets; row&7 == lm&7 so ks=1 toggles via ^32
  int aoffs[8], boffs[4];
#pragma unroll
  for (int i = 0; i < 8; ++i) {
    int ra = wr * 128 + i * 16 + lm;
    aoffs[i] = ra * 64 + ((q4 ^ (ra & 7)) * 8);
  }
#pragma unroll
  for (int j = 0; j < 4; ++j) {
    int rb = wc * 64 + j * 16 + lm;
    boffs[j] = rb * 64 + ((q4 ^ (rb & 7)) * 8);
  }

  f32x4 acc[8][4] = {};
  bf16x8 af[4][2];    // current i-half (4 rows-frags x 2 ks)
  bf16x8 bfr[4][2];   // all 4 j x 2 ks, live across phases

  // prologue: tiles 0 and 1 (8 loads each); wait tile0 (counted), barrier
  STG(0); STG(1);
  asm volatile("s_waitcnt vmcnt(8)" ::: "memory");
  __builtin_amdgcn_s_barrier();

  for (int t = 0; t < 16; ++t) {
    const u16* Ab = smem + (t & 1) * 32768;
    const u16* Bb = Ab + 16384;

    // ---- phase 1: read A(i0-3)+B(j0-1) [12 reads]; MFMA (i0-3, j0-1) ----
#pragma unroll
    for (int i = 0; i < 4; ++i) {
      af[i][0] = *(const bf16x8*)(Ab + aoffs[i]);
      af[i][1] = *(const bf16x8*)(Ab + (aoffs[i] ^ 32));
    }
#pragma unroll
    for (int j = 0; j < 2; ++j) {
      bfr[j][0] = *(const bf16x8*)(Bb + boffs[j]);
      bfr[j][1] = *(const bf16x8*)(Bb + (boffs[j] ^ 32));
    }
    __builtin_amdgcn_s_barrier();
    __builtin_amdgcn_s_setprio(1);
#pragma unroll
    for (int i = 0; i < 4; ++i)
#pragma unroll
      for (int j = 0; j < 2; ++j) {
        acc[i][j] = __builtin_amdgcn_mfma_f32_16x16x32_bf16(af[i][0], bfr[j][0], acc[i][j], 0, 0, 0);
        acc[i][j] = __builtin_amdgcn_mfma_f32_16x16x32_bf16(af[i][1], bfr[j][1], acc[i][j], 0, 0, 0);
      }
    __builtin_amdgcn_s_setprio(0);
    __builtin_amdgcn_s_barrier();

    // ---- phase 2: read B(j2-3) [4 reads]; MFMA (i0-3, j2-3) ----
#pragma unroll
    for (int j = 2; j < 4; ++j) {
      bfr[j][0] = *(const bf16x8*)(Bb + boffs[j]);
      bfr[j][1] = *(const bf16x8*)(Bb + (boffs[j] ^ 32));
    }
    __builtin_amdgcn_s_barrier();
    __builtin_amdgcn_s_setprio(1);
#pragma unroll
    for (int i = 0; i < 4; ++i)
#pragma unroll
      for (int j = 2; j < 4; ++j) {
        acc[i][j] = __builtin_amdgcn_mfma_f32_16x16x32_bf16(af[i][0], bfr[j][0], acc[i][j], 0, 0, 0);
        acc[i][j] = __builtin_amdgcn_mfma_f32_16x16x32_bf16(af[i][1], bfr[j][1], acc[i][j], 0, 0, 0);
      }
    __builtin_amdgcn_s_setprio(0);
    __builtin_amdgcn_s_barrier();

    // ---- phase 3: read A(i4-7) [8 reads, LAST reads of buf(t)]; MFMA (i4-7, j2-3) ----
#pragma unroll
    for (int i = 0; i < 4; ++i) {
      af[i][0] = *(const bf16x8*)(Ab + aoffs[i + 4]);
      af[i][1] = *(const bf16x8*)(Ab + (aoffs[i + 4] ^ 32));
    }
    __builtin_amdgcn_s_barrier();
    __builtin_amdgcn_s_setprio(1);
#pragma unroll
    for (int i = 0; i < 4; ++i)
#pragma unroll
      for (int j = 2; j < 4; ++j) {
        acc[i + 4][j] = __builtin_amdgcn_mfma_f32_16x16x32_bf16(af[i][0], bfr[j][0], acc[i + 4][j], 0, 0, 0);
        acc[i + 4][j] = __builtin_amdgcn_mfma_f32_16x16x32_bf16(af[i][1], bfr[j][1], acc[i + 4][j], 0, 0, 0);
      }
    __builtin_amdgcn_s_setprio(0);
    __builtin_amdgcn_s_barrier();
    // buf(t) is LDS-dead for ALL waves past this barrier (their ph3 reads
    // completed before their ph3 MFMAs). Pin any sinking reads:
    asm volatile("" ::: "memory");

    // ---- phase 4: stage tile t+2 into buf(t); MFMA (i4-7, j0-1) [reg reuse] ----
    if (t < 14) STG(t + 2);
    __builtin_amdgcn_s_barrier();
    __builtin_amdgcn_s_setprio(1);
#pragma unroll
    for (int i = 0; i < 4; ++i)
#pragma unroll
      for (int j = 0; j < 2; ++j) {
        acc[i + 4][j] = __builtin_amdgcn_mfma_f32_16x16x32_bf16(af[i][0], bfr[j][0], acc[i + 4][j], 0, 0, 0);
        acc[i + 4][j] = __builtin_amdgcn_mfma_f32_16x16x32_bf16(af[i][1], bfr[j][1], acc[i + 4][j], 0, 0, 0);
      }
    __builtin_amdgcn_s_setprio(0);
    if (t < 14) {
      asm volatile("s_waitcnt vmcnt(8)" ::: "memory");   // next tile resident
    } else if (t == 14) {
      asm volatile("s_waitcnt vmcnt(0)" ::: "memory");   // drain tile 15
    }
    __builtin_amdgcn_s_barrier();
  }
#undef STG

  __syncthreads();   // full fence before smem reuse as C-tile

  // ---- epilogue: LDS round-trip, 256x256 C-tile (exactly 128 KiB) ----
  u16* TT = smem;
  const int ccb = tileN & 1023;
  const int proj = tileN >> 10;               // uniform per block
  const float scl = (proj == 0 ? QSCALE : 1.0f);
  const float* bp = (proj == 0 ? b0 : (proj == 1 ? b1 : b2));
#pragma unroll
  for (int j = 0; j < 4; ++j) {
    const int ncl = wc * 64 + j * 16 + lm;
    const float bs = bp[ccb + ncl];
#pragma unroll
    for (int i = 0; i < 8; ++i) {
      const int m0 = wr * 128 + i * 16 + q4 * 4;
      f32x4 vv;
#pragma unroll
      for (int r = 0; r < 4; ++r) vv[r] = (acc[i][j][r] + bs) * scl;
      bf16x4 ov = __builtin_convertvector(vv, bf16x4);
      if (proj < 2) {
        // orientation A: (m, n) at m*256 + (n ^ 8*(m&15))
        ushort4 us = *(ushort4*)&ov;
        TT[(m0 + 0) * 256 + (ncl ^ (8 * ((m0 + 0) & 15)))] = us.x;
        TT[(m0 + 1) * 256 + (ncl ^ (8 * ((m0 + 1) & 15)))] = us.y;
        TT[(m0 + 2) * 256 + (ncl ^ (8 * ((m0 + 2) & 15)))] = us.z;
        TT[(m0 + 3) * 256 + (ncl ^ (8 * ((m0 + 3) & 15)))] = us.w;
      } else {
        // orientation B: (n, m) at n*256 + (m ^ 8*(n&15))
        *(bf16x4*)(TT + ncl * 256 + (m0 ^ (8 * (ncl & 15)))) = ov;
      }
    }
  }
  __syncthreads();
  if (proj < 2) {
    u16* optr = (proj == 0 ? oQ : oK);
#pragma unroll
    for (int it = 0; it < 16; ++it) {
      int seg = it * 512 + tid;
      int ml = seg >> 5, sc = (seg & 31) * 8;
      uint4 val = *(const uint4*)(TT + ml * 256 + (sc ^ (8 * (ml & 15))));
      *(uint4*)(optr + (size_t)(tileM + ml) * 1024 + ccb + sc) = val;
    }
  } else {
    const int bb = tileM >> 11, s0v = tileM & 2047;
#pragma unroll
    for (int it = 0; it < 16; ++it) {
      int seg = it * 512 + tid;
      int ccl = seg >> 5, sc = (seg & 31) * 8;
      uint4 val = *(const uint4*)(TT + ccl * 256 + (sc ^ (8 * (ccl & 15))));
      int cc = ccb + ccl, hh = cc >> 6, dd = cc & 63;
      *(uint4*)(oV + ((size_t)(bb * 16 + hh) * 64 + dd) * 2048 + s0v + sc) = val;
    }
  }
}

// ---------------- GEMM (out-proj): C[M][1024] = zB * woT^T, 64x128 tiles ----
// R8 measured: this 4-blocks/CU config beat the old 128x128 2-blocks/CU by
// ~5 us total. Keep.
__global__ __launch_bounds__(256) void gemm_o_kernel(
    const u16* __restrict__ A, const u16* __restrict__ Bt,
    const float* __restrict__ bo, float* __restrict__ oF) {
  constexpr int K = 1024;
  __shared__ __align__(16) u16 smem[(64 + 128) * 64];   // As(64x64) | Bs(128x64)
  u16* As = smem;
  u16* Bs = smem + 64 * 64;
  const int tid = threadIdx.x;
  const int lane = tid & 63, wv = tid >> 6;
  const int wm = (wv >> 1) * 32, wn = (wv & 1) * 64;
  const int q4 = lane >> 4, lm = lane & 15;

  // XCD-bijective swizzle over 1024 blocks (1024 % 8 == 0)
  const int bid = blockIdx.x;
  const int wg = (bid & 7) * 128 + (bid >> 3);
  const int tileN = (wg & 7) * 128, tileM = (wg >> 3) * 64;

  const u16* gA[2]; const u16* gB[4]; u16* lA[2]; u16* lB[4];
#pragma unroll
  for (int rr = 0; rr < 2; ++rr) {
    int c = rr * 256 + tid;
    int r = c >> 3, sw = ((c & 7) ^ (r & 7)) * 8;
    gA[rr] = A + (size_t)(tileM + r) * K + sw;
    lA[rr] = As + c * 8;
  }
#pragma unroll
  for (int rr = 0; rr < 4; ++rr) {
    int c = rr * 256 + tid;
    int r = c >> 3, sw = ((c & 7) ^ (r & 7)) * 8;
    gB[rr] = Bt + (size_t)(tileN + r) * K + sw;
    lB[rr] = Bs + c * 8;
  }

  f32x4 acc[2][4] = {};

  int aoff[2][2], boff[2][4];
#pragma unroll
  for (int ks = 0; ks < 2; ++ks) {
#pragma unroll
    for (int i = 0; i < 2; ++i) {
      int ra = wm + i * 16 + lm;
      aoff[ks][i] = ra * 64 + (((ks * 4 + q4) ^ (ra & 7)) * 8);
    }
#pragma unroll
    for (int j = 0; j < 4; ++j) {
      int rb = wn + j * 16 + lm;
      boff[ks][j] = rb * 64 + (((ks * 4 + q4) ^ (rb & 7)) * 8);
    }
  }

  for (int k0 = 0; k0 < K; k0 += 64) {
#pragma unroll
    for (int rr = 0; rr < 2; ++rr) g2l16(gA[rr] + k0, lA[rr]);
#pragma unroll
    for (int rr = 0; rr < 4; ++rr) g2l16(gB[rr] + k0, lB[rr]);
    __syncthreads();
#pragma unroll
    for (int ks = 0; ks < 2; ++ks) {
      bf16x8 af[2], bf[4];
#pragma unroll
      for (int i = 0; i < 2; ++i) af[i] = *(const bf16x8*)(As + aoff[ks][i]);
#pragma unroll
      for (int j = 0; j < 4; ++j) bf[j] = *(const bf16x8*)(Bs + boff[ks][j]);
#pragma unroll
      for (int i = 0; i < 2; ++i)
#pragma unroll
        for (int j = 0; j < 4; ++j)
          acc[i][j] = __builtin_amdgcn_mfma_f32_16x16x32_bf16(af[i], bf[j], acc[i][j], 0, 0, 0);
    }
    __syncthreads();
  }

#pragma unroll
  for (int j = 0; j < 4; ++j) {
    int n = tileN + wn + j * 16 + lm;
    float bs = bo[n];
#pragma unroll
    for (int i = 0; i < 2; ++i) {
      int m0 = tileM + wm + i * 16 + q4 * 4;
#pragma unroll
      for (int r = 0; r < 4; ++r) oF[(m0 + r) * HD_ + n] = acc[i][j][r] + bs;
    }
  }
}

// ---------------- flash attention — R4 proven config (do not touch) --------
// R4/R8 measured: 74-76.5 us, VGPR 56, occupancy 34%. R5's QK-one-tile-ahead
// pipeline REGRESSED to 92 us (MFMA-busy unchanged, +15 us stall) — do not
// re-pipeline this loop at source level.
// KEY PERMUTATION: K rows staged at LDS slot s = kb*16+q4*4+r hold logical
// key kperm(s) = (kb&1)*32 + q4*8 + (kb>>1)*4 + r. The S^T-MFMA C-layout
// output IS the PV A-fragment layout per-lane; V keeps sequential key order.
// P never touches LDS.
// REGISTER RULE: keep launch_bounds (256,2); tighter -> spill storm.
__global__ __launch_bounds__(256, 2) void flash_kernel(
    const u16* __restrict__ Q, const u16* __restrict__ Kb,
    const u16* __restrict__ Vt, u16* __restrict__ Z) {
  __shared__ __align__(16) u16 Ks[2][64 * 64];   // [slot][d] swizzled, key-permuted
  __shared__ __align__(16) u16 Vs[2][64 * 64];   // [d][key] swizzled, sequential
  const int tid = threadIdx.x, lane = tid & 63, wv = tid >> 6;
  const int q4 = lane >> 4, lm = lane & 15;

  const int bid = blockIdx.x;
  const int bh = bid >> 4, qt = bid & 15;        // 16 consecutive blocks share (b,h) K/V
  const int b = bh >> 4, h = bh & 15;

  const u16* qbase = Q + ((size_t)(b * S_ + qt * 128)) * HD_ + h * DH_;
  const u16* kbase = Kb + (size_t)b * S_ * HD_ + h * DH_;
  const u16* vbase = Vt + ((size_t)(b * H_ + h)) * DH_ * S_;
  u16* zbase = Z + ((size_t)(b * S_ + qt * 128)) * HD_ + h * DH_;

  const int c0 = tid,       r0 = c0 >> 3, s0 = ((c0 & 7) ^ (r0 & 7)) * 8;
  const int c1 = tid + 256, r1 = c1 >> 3, s1 = ((c1 & 7) ^ (r1 & 7)) * 8;
  const int kr0 = ((r0 >> 4) & 1) * 32 + ((r0 >> 2) & 3) * 8 + (r0 >> 5) * 4 + (r0 & 3);
  const int kr1 = ((r1 >> 4) & 1) * 32 + ((r1 >> 2) & 3) * 8 + (r1 >> 5) * 4 + (r1 & 3);

  bf16x8 qf[2][2];
#pragma unroll
  for (int qs = 0; qs < 2; ++qs)
#pragma unroll
    for (int dc = 0; dc < 2; ++dc)
      qf[qs][dc] = *(const bf16x8*)(qbase + (wv * 32 + qs * 16 + lm) * HD_ + dc * 32 + q4 * 8);

  const bf16x8 ones = {(__bf16)1.f, (__bf16)1.f, (__bf16)1.f, (__bf16)1.f,
                       (__bf16)1.f, (__bf16)1.f, (__bf16)1.f, (__bf16)1.f};

  // fragment base offsets (d-chunk 0 / 1); kb/db contribute imm kb*1024/db*1024
  const int base0 = lm * 64 + ((q4 ^ (lm & 7)) * 8);
  const int base1 = lm * 64 + (((4 + q4) ^ (lm & 7)) * 8);

  f32x4 oacc[2][4] = {};
  f32x4 liacc[2] = {};

  {
    g2l16(kbase + kr0 * HD_ + s0, Ks[0] + c0 * 8);
    g2l16(kbase + kr1 * HD_ + s1, Ks[0] + c1 * 8);
    g2l16(vbase + r0 * S_ + s0, Vs[0] + c0 * 8);
    g2l16(vbase + r1 * S_ + s1, Vs[0] + c1 * 8);
  }

  for (int t = 0; t < 32; ++t) {
    const int pb = t & 1;
    __syncthreads();
    if (t < 31) {
      const u16* kt = kbase + (size_t)(t + 1) * 64 * HD_;
      const u16* vt = vbase + (t + 1) * 64;
      g2l16(kt + kr0 * HD_ + s0, Ks[1 - pb] + c0 * 8);
      g2l16(kt + kr1 * HD_ + s1, Ks[1 - pb] + c1 * 8);
      g2l16(vt + r0 * S_ + s0, Vs[1 - pb] + c0 * 8);
      g2l16(vt + r1 * S_ + s1, Vs[1 - pb] + c1 * 8);
    }
    const u16* Kp = Ks[pb];
    const u16* Vp = Vs[pb];

#pragma unroll
    for (int ck = 0; ck < 2; ++ck) {
      bf16x8 ka0 = *(const bf16x8*)(Kp + ck * 1024 + base0);
      bf16x8 ka1 = *(const bf16x8*)(Kp + ck * 1024 + base1);
      bf16x8 kb0 = *(const bf16x8*)(Kp + (ck + 2) * 1024 + base0);
      bf16x8 kb1 = *(const bf16x8*)(Kp + (ck + 2) * 1024 + base1);
      bf16x8 pf[2];
#pragma unroll
      for (int qs = 0; qs < 2; ++qs) {
        f32x4 sa = {}, sb = {};
        sa = __builtin_amdgcn_mfma_f32_16x16x32_bf16(ka0, qf[qs][0], sa, 0, 0, 0);
        sa = __builtin_amdgcn_mfma_f32_16x16x32_bf16(ka1, qf[qs][1], sa, 0, 0, 0);
        sb = __builtin_amdgcn_mfma_f32_16x16x32_bf16(kb0, qf[qs][0], sb, 0, 0, 0);
        sb = __builtin_amdgcn_mfma_f32_16x16x32_bf16(kb1, qf[qs][1], sb, 0, 0, 0);
        f32x4 pa, pb2;
#pragma unroll
        for (int r = 0; r < 4; ++r) { pa[r] = EXP2F(sa[r]); pb2[r] = EXP2F(sb[r]); }
        bf16x4 la = __builtin_convertvector(pa, bf16x4);
        bf16x4 lb = __builtin_convertvector(pb2, bf16x4);
        pf[qs] = __builtin_shufflevector(la, lb, 0, 1, 2, 3, 4, 5, 6, 7);
      }
      const int vsel = ck ? base1 : base0;
      __builtin_amdgcn_s_setprio(1);
#pragma unroll
      for (int qs = 0; qs < 2; ++qs)
        liacc[qs] = __builtin_amdgcn_mfma_f32_16x16x32_bf16(pf[qs], ones, liacc[qs], 0, 0, 0);
#pragma unroll
      for (int db = 0; db < 4; ++db) {
        bf16x8 vf = *(const bf16x8*)(Vp + db * 1024 + vsel);
#pragma unroll
        for (int qs = 0; qs < 2; ++qs)
          oacc[qs][db] = __builtin_amdgcn_mfma_f32_16x16x32_bf16(pf[qs], vf, oacc[qs][db], 0, 0, 0);
      }
      __builtin_amdgcn_s_setprio(0);
    }
  }

  // ---- normalize + store (wave owns its 32 q-rows; li is in-lane) ----
#pragma unroll
  for (int qs = 0; qs < 2; ++qs) {
    float rin[4];
#pragma unroll
    for (int r = 0; r < 4; ++r) rin[r] = 1.f / liacc[qs][r];
#pragma unroll
    for (int db = 0; db < 4; ++db) {
      f32x4 vv;
#pragma unroll
      for (int r = 0; r < 4; ++r) vv[r] = oacc[qs][db][r] * rin[r];
      bf16x4 ov = __builtin_convertvector(vv, bf16x4);
      ushort4 us = *(ushort4*)&ov;
      int m0 = wv * 32 + qs * 16 + q4 * 4;
      zbase[(m0 + 0) * HD_ + db * 16 + lm] = us.x;
      zbase[(m0 + 1) * HD_ + db * 16 + lm] = us.y;
      zbase[(m0 + 2) * HD_ + db * 16 + lm] = us.z;
      zbase[(m0 + 3) * HD_ + db * 16 + lm] = us.w;
    }
  }
}

// ---------------- host ----------------
extern "C" void kernel_launch(void* const* d_in, const int* in_sizes, int n_in,
                              void* d_out, int out_size, void* d_ws, size_t ws_size,
                              hipStream_t stream) {
  const float* x  = (const float*)d_in[0];
  const float* Wq = (const float*)d_in[1];
  const float* bq = (const float*)d_in[2];
  const float* Wk = (const float*)d_in[3];
  const float* bk = (const float*)d_in[4];
  const float* Wv = (const float*)d_in[5];
  const float* bv = (const float*)d_in[6];
  const float* Wo = (const float*)d_in[7];
  const float* bo = (const float*)d_in[8];
  float* out = (float*)d_out;

  char* w = (char*)d_ws;
  u16*   xb    = (u16*)w;   w += (size_t)M_ * E_ * 2;
  u16*   wqkvT = (u16*)w;   w += (size_t)3 * HD_ * E_ * 2;
  u16*   woT   = (u16*)w;   w += (size_t)E_ * HD_ * 2;
  u16*   qB    = (u16*)w;   w += (size_t)M_ * HD_ * 2;
  u16*   kB    = (u16*)w;   w += (size_t)M_ * HD_ * 2;
  u16*   vT    = (u16*)w;   w += (size_t)M_ * HD_ * 2;     // V^T written by gemm0
  u16*   zB    = (u16*)w;   w += (size_t)M_ * HD_ * 2;

  prep_kernel<<<dim3(9216), 256, 0, stream>>>(x, Wq, Wk, Wv, Wo, xb, wqkvT, woT);
  gemm_qkv_kernel<<<dim3(384), 512, 0, stream>>>(xb, wqkvT, bq, bk, bv, qB, kB, vT);
  flash_kernel<<<dim3(1024), 256, 0, stream>>>(qB, kB, vT, zB);
  gemm_o_kernel<<<dim3(1024), 256, 0, stream>>>(zB, woT, bo, out);
}

// Round 12
// 270.339 us; speedup vs baseline: 1.0427x; 1.0427x over previous
//
#include <hip/hip_runtime.h>
#include <hip/hip_bf16.h>

#define B_  4
#define S_  2048
#define E_  1024
#define H_  16
#define DH_ 64
#define M_  (B_*S_)    // 8192 rows
#define HD_ (H_*DH_)   // 1024

typedef unsigned short u16;
typedef __attribute__((ext_vector_type(8))) __bf16 bf16x8;
typedef __attribute__((ext_vector_type(4))) __bf16 bf16x4;
typedef __attribute__((ext_vector_type(4))) float  f32x4;

#if __has_builtin(__builtin_amdgcn_exp2f)
#define EXP2F __builtin_amdgcn_exp2f
#else
#define EXP2F __builtin_exp2f
#endif

// softmax scale folded into Q at QKV epilogue: 1/sqrt(64) * log2(e)
#define QSCALE 0.18033688011112042f

// ---- async global->LDS, 16B per lane ----
__device__ __forceinline__ void g2l16(const void* g, void* l) {
  __builtin_amdgcn_global_load_lds(
      (const __attribute__((address_space(1))) void*)g,
      (__attribute__((address_space(3))) void*)l, 16, 0, 0);
}

// RNE float -> bf16 bits (scalar path, used in prep only)
__device__ __forceinline__ u16 f2bf(float f) {
  union { float f; unsigned u; } v; v.f = f;
  unsigned r = v.u + 0x7FFFu + ((v.u >> 16) & 1u);
  return (u16)(r >> 16);
}

// ---------------- fused prep: cvt_x | pack_wqkv | pack_wo ----------------
__global__ __launch_bounds__(256) void prep_kernel(
    const float* __restrict__ x, const float* __restrict__ Wq,
    const float* __restrict__ Wk, const float* __restrict__ Wv,
    const float* __restrict__ Wo,
    u16* __restrict__ xb, u16* __restrict__ wqkvT, u16* __restrict__ woT) {
  __shared__ u16 tile[64][66];
  const int blk = blockIdx.x, tid = threadIdx.x;
  if (blk < 8192) {
    int i = blk * 256 + tid;
    float4 v = ((const float4*)x)[i];
    ushort4 o;
    o.x = f2bf(v.x); o.y = f2bf(v.y); o.z = f2bf(v.z); o.w = f2bf(v.w);
    ((ushort4*)xb)[i] = o;
  } else if (blk < 8960) {
    int b2 = blk - 8192;
    int p = b2 >> 8, h = (b2 >> 4) & 15, e0 = (b2 & 15) * 64;
    const float* src = (p == 0 ? Wq : (p == 1 ? Wk : Wv)) + h * (E_ * DH_);
#pragma unroll
    for (int r = 0; r < 16; ++r) {
      int idx = r * 256 + tid;
      int el = idx >> 6, d = idx & 63;
      tile[el][d] = f2bf(src[(e0 + el) * DH_ + d]);
    }
    __syncthreads();
    u16* dst = wqkvT + (p * HD_ + h * DH_) * E_;
#pragma unroll
    for (int r = 0; r < 16; ++r) {
      int idx = r * 256 + tid;
      int d = idx >> 6, el = idx & 63;
      dst[d * E_ + e0 + el] = tile[el][d];
    }
  } else {
    int b3 = blk - 8960;
    int c0 = (b3 >> 4) * 64, e0 = (b3 & 15) * 64;
#pragma unroll
    for (int r = 0; r < 16; ++r) {
      int idx = r * 256 + tid;
      int cl = idx >> 6, el = idx & 63;
      tile[cl][el] = f2bf(Wo[(c0 + cl) * E_ + e0 + el]);
    }
    __syncthreads();
#pragma unroll
    for (int r = 0; r < 16; ++r) {
      int idx = r * 256 + tid;
      int er = idx >> 6, cl = idx & 63;
      woT[(e0 + er) * HD_ + c0 + cl] = tile[cl][er];
    }
  }
}

// ---------------- GEMM (QKV): C[M][3072] = xb * wqkvT^T, 128x128 tiles ----
// QKV epilogue — bias, bf16, then LDS round-trip to emit 16B coalesced
// stores. Q/K in [m][cc] orientation; V written DIRECTLY as V^T [b,h,d,s].
// SCHEDULE IS FROZEN (3 failed restructures):
//  R3:  2-phase/counted-vmcnt 128x256 graft  -> neutral (== this kernel)
//  R11: 4-quadrant-phase 256^2 "template port" -> 82 us, MfmaUtil 24%
//       (vs ~57 us this kernel), ~90% stall at 1 blk/CU lockstep.
// Gains from the 8-phase family require the EXACT template (half-tile
// staging, counted lgkmcnt, vmcnt(6) 3-in-flight) — not reproducible here
// without .s inspection. Only index-level changes allowed.
// R12: T1 XCD-bijective swizzle — 1536 blocks = 8 XCD x (3 N-tiles x 64 M).
// Each XCD owns a 3-tile N-stripe: B-panel 768 KB stays L2-resident
// (old 2D dispatch spread all 24 N-tiles across XCDs -> 6 MB B thrash).
__global__ __launch_bounds__(256) void gemm_qkv_kernel(
    const u16* __restrict__ A, const u16* __restrict__ Bt,
    const float* __restrict__ b0, const float* __restrict__ b1,
    const float* __restrict__ b2,
    u16* __restrict__ oQ, u16* __restrict__ oK, u16* __restrict__ oV) {
  constexpr int K = 1024;
  __shared__ __align__(16) u16 smem[2 * 128 * 64];   // As | Bs; reused as C-tile
  u16* As = smem;
  u16* Bs = smem + 128 * 64;
  const int tid = threadIdx.x;
  const int lane = tid & 63, wv = tid >> 6;
  const int wm = (wv >> 1) * 64, wn = (wv & 1) * 64;
  const int q4 = lane >> 4, lm = lane & 15;

  // XCD-bijective: bid -> (xcd, n_local 0..2, m 0..63)
  const int bid = blockIdx.x;
  const int xcd = bid & 7, idx = bid >> 3;
  const int tileN = (xcd * 3 + (idx >> 6)) * 128;
  const int tileM = (idx & 63) * 128;

  const u16* gA[4]; const u16* gB[4]; u16* lA[4]; u16* lB[4];
#pragma unroll
  for (int rr = 0; rr < 4; ++rr) {
    int c = rr * 256 + tid;
    int r = c >> 3, sw = ((c & 7) ^ (r & 7)) * 8;
    gA[rr] = A + (size_t)(tileM + r) * K + sw;
    gB[rr] = Bt + (size_t)(tileN + r) * K + sw;
    lA[rr] = As + c * 8;
    lB[rr] = Bs + c * 8;
  }

  f32x4 acc[4][4] = {};

  int aoff[2][4], boff[2][4];
#pragma unroll
  for (int ks = 0; ks < 2; ++ks) {
#pragma unroll
    for (int i = 0; i < 4; ++i) {
      int ra = wm + i * 16 + lm;
      aoff[ks][i] = ra * 64 + (((ks * 4 + q4) ^ (ra & 7)) * 8);
      int rb = wn + i * 16 + lm;
      boff[ks][i] = rb * 64 + (((ks * 4 + q4) ^ (rb & 7)) * 8);
    }
  }

  for (int k0 = 0; k0 < K; k0 += 64) {
#pragma unroll
    for (int rr = 0; rr < 4; ++rr) {
      g2l16(gA[rr] + k0, lA[rr]);
      g2l16(gB[rr] + k0, lB[rr]);
    }
    __syncthreads();
#pragma unroll
    for (int ks = 0; ks < 2; ++ks) {
      bf16x8 af[4], bf[4];
#pragma unroll
      for (int i = 0; i < 4; ++i) af[i] = *(const bf16x8*)(As + aoff[ks][i]);
#pragma unroll
      for (int j = 0; j < 4; ++j) bf[j] = *(const bf16x8*)(Bs + boff[ks][j]);
#pragma unroll
      for (int i = 0; i < 4; ++i)
#pragma unroll
        for (int j = 0; j < 4; ++j)
          acc[i][j] = __builtin_amdgcn_mfma_f32_16x16x32_bf16(af[i], bf[j], acc[i][j], 0, 0, 0);
    }
    __syncthreads();
  }

  // ---- LDS round-trip epilogue (after final barrier, smem is free) ----
  u16* TT = smem;                        // 128 x 128 bf16, swizzled
  const int ccb = tileN & 1023;
  const int proj = tileN >> 10;          // uniform per block
  const float scl = (proj == 0 ? QSCALE : 1.0f);
  const float* bp = (proj == 0 ? b0 : (proj == 1 ? b1 : b2));
#pragma unroll
  for (int j = 0; j < 4; ++j) {
    int ncl = wn + j * 16 + lm;
    float bs = bp[ccb + ncl];
#pragma unroll
    for (int i = 0; i < 4; ++i) {
      int m0 = wm + i * 16 + q4 * 4;
      f32x4 vv;
#pragma unroll
      for (int r = 0; r < 4; ++r) vv[r] = (acc[i][j][r] + bs) * scl;
      bf16x4 ov = __builtin_convertvector(vv, bf16x4);
      if (proj < 2) {
        // orientation A: element (ml, ccl) at ml*128 + (ccl ^ 8*(ml&15))
        ushort4 us = *(ushort4*)&ov;
        TT[(m0 + 0) * 128 + (ncl ^ (8 * ((m0 + 0) & 15)))] = us.x;
        TT[(m0 + 1) * 128 + (ncl ^ (8 * ((m0 + 1) & 15)))] = us.y;
        TT[(m0 + 2) * 128 + (ncl ^ (8 * ((m0 + 2) & 15)))] = us.z;
        TT[(m0 + 3) * 128 + (ncl ^ (8 * ((m0 + 3) & 15)))] = us.w;
      } else {
        // orientation B: element (ccl, ml) at ccl*128 + (ml ^ 8*(ccl&15))
        *(bf16x4*)(TT + ncl * 128 + (m0 ^ (8 * (ncl & 15)))) = ov;  // b64
      }
    }
  }
  __syncthreads();
  if (proj < 2) {
    u16* optr = (proj == 0 ? oQ : oK);
#pragma unroll
    for (int rr = 0; rr < 8; ++rr) {
      int seg = rr * 256 + tid;
      int ml = seg >> 4, sc = (seg & 15) * 8;
      uint4 val = *(const uint4*)(TT + ml * 128 + (sc ^ (8 * (ml & 15))));
      *(uint4*)(optr + (size_t)(tileM + ml) * 1024 + ccb + sc) = val;
    }
  } else {
    const int bb = tileM >> 11, s0 = tileM & 2047;
#pragma unroll
    for (int rr = 0; rr < 8; ++rr) {
      int seg = rr * 256 + tid;
      int ccl = seg >> 4, sc = (seg & 15) * 8;
      int cc = ccb + ccl;
      int hh = cc >> 6, dd = cc & 63;
      uint4 val = *(const uint4*)(TT + ccl * 128 + (sc ^ (8 * (ccl & 15))));
      *(uint4*)(oV + ((size_t)(bb * 16 + hh) * 64 + dd) * 2048 + s0 + sc) = val;
    }
  }
}

// ---------------- GEMM (out-proj): C[M][1024] = zB * woT^T, 64x128 tiles ----
// R8 measured: this 4-blocks/CU config beat the old 128x128 2-blocks/CU by
// ~5 us total. Keep.
__global__ __launch_bounds__(256) void gemm_o_kernel(
    const u16* __restrict__ A, const u16* __restrict__ Bt,
    const float* __restrict__ bo, float* __restrict__ oF) {
  constexpr int K = 1024;
  __shared__ __align__(16) u16 smem[(64 + 128) * 64];   // As(64x64) | Bs(128x64)
  u16* As = smem;
  u16* Bs = smem + 64 * 64;
  const int tid = threadIdx.x;
  const int lane = tid & 63, wv = tid >> 6;
  const int wm = (wv >> 1) * 32, wn = (wv & 1) * 64;
  const int q4 = lane >> 4, lm = lane & 15;

  // XCD-bijective swizzle over 1024 blocks (1024 % 8 == 0)
  const int bid = blockIdx.x;
  const int wg = (bid & 7) * 128 + (bid >> 3);
  const int tileN = (wg & 7) * 128, tileM = (wg >> 3) * 64;

  const u16* gA[2]; const u16* gB[4]; u16* lA[2]; u16* lB[4];
#pragma unroll
  for (int rr = 0; rr < 2; ++rr) {
    int c = rr * 256 + tid;
    int r = c >> 3, sw = ((c & 7) ^ (r & 7)) * 8;
    gA[rr] = A + (size_t)(tileM + r) * K + sw;
    lA[rr] = As + c * 8;
  }
#pragma unroll
  for (int rr = 0; rr < 4; ++rr) {
    int c = rr * 256 + tid;
    int r = c >> 3, sw = ((c & 7) ^ (r & 7)) * 8;
    gB[rr] = Bt + (size_t)(tileN + r) * K + sw;
    lB[rr] = Bs + c * 8;
  }

  f32x4 acc[2][4] = {};

  int aoff[2][2], boff[2][4];
#pragma unroll
  for (int ks = 0; ks < 2; ++ks) {
#pragma unroll
    for (int i = 0; i < 2; ++i) {
      int ra = wm + i * 16 + lm;
      aoff[ks][i] = ra * 64 + (((ks * 4 + q4) ^ (ra & 7)) * 8);
    }
#pragma unroll
    for (int j = 0; j < 4; ++j) {
      int rb = wn + j * 16 + lm;
      boff[ks][j] = rb * 64 + (((ks * 4 + q4) ^ (rb & 7)) * 8);
    }
  }

  for (int k0 = 0; k0 < K; k0 += 64) {
#pragma unroll
    for (int rr = 0; rr < 2; ++rr) g2l16(gA[rr] + k0, lA[rr]);
#pragma unroll
    for (int rr = 0; rr < 4; ++rr) g2l16(gB[rr] + k0, lB[rr]);
    __syncthreads();
#pragma unroll
    for (int ks = 0; ks < 2; ++ks) {
      bf16x8 af[2], bf[4];
#pragma unroll
      for (int i = 0; i < 2; ++i) af[i] = *(const bf16x8*)(As + aoff[ks][i]);
#pragma unroll
      for (int j = 0; j < 4; ++j) bf[j] = *(const bf16x8*)(Bs + boff[ks][j]);
#pragma unroll
      for (int i = 0; i < 2; ++i)
#pragma unroll
        for (int j = 0; j < 4; ++j)
          acc[i][j] = __builtin_amdgcn_mfma_f32_16x16x32_bf16(af[i], bf[j], acc[i][j], 0, 0, 0);
    }
    __syncthreads();
  }

#pragma unroll
  for (int j = 0; j < 4; ++j) {
    int n = tileN + wn + j * 16 + lm;
    float bs = bo[n];
#pragma unroll
    for (int i = 0; i < 2; ++i) {
      int m0 = tileM + wm + i * 16 + q4 * 4;
#pragma unroll
      for (int r = 0; r < 4; ++r) oF[(m0 + r) * HD_ + n] = acc[i][j][r] + bs;
    }
  }
}

// ---------------- flash attention — R4 proven config (do not touch) --------
// R4/R8 measured: 74-76.5 us, VGPR 56, occupancy 34%. R5's QK-one-tile-ahead
// pipeline REGRESSED to 92 us (MFMA-busy unchanged, +15 us stall) — do not
// re-pipeline this loop at source level.
// KEY PERMUTATION: K rows staged at LDS slot s = kb*16+q4*4+r hold logical
// key kperm(s) = (kb&1)*32 + q4*8 + (kb>>1)*4 + r. The S^T-MFMA C-layout
// output IS the PV A-fragment layout per-lane; V keeps sequential key order.
// P never touches LDS.
// REGISTER RULE: keep launch_bounds (256,2); tighter -> spill storm.
__global__ __launch_bounds__(256, 2) void flash_kernel(
    const u16* __restrict__ Q, const u16* __restrict__ Kb,
    const u16* __restrict__ Vt, u16* __restrict__ Z) {
  __shared__ __align__(16) u16 Ks[2][64 * 64];   // [slot][d] swizzled, key-permuted
  __shared__ __align__(16) u16 Vs[2][64 * 64];   // [d][key] swizzled, sequential
  const int tid = threadIdx.x, lane = tid & 63, wv = tid >> 6;
  const int q4 = lane >> 4, lm = lane & 15;

  const int bid = blockIdx.x;
  const int bh = bid >> 4, qt = bid & 15;        // 16 consecutive blocks share (b,h) K/V
  const int b = bh >> 4, h = bh & 15;

  const u16* qbase = Q + ((size_t)(b * S_ + qt * 128)) * HD_ + h * DH_;
  const u16* kbase = Kb + (size_t)b * S_ * HD_ + h * DH_;
  const u16* vbase = Vt + ((size_t)(b * H_ + h)) * DH_ * S_;
  u16* zbase = Z + ((size_t)(b * S_ + qt * 128)) * HD_ + h * DH_;

  const int c0 = tid,       r0 = c0 >> 3, s0 = ((c0 & 7) ^ (r0 & 7)) * 8;
  const int c1 = tid + 256, r1 = c1 >> 3, s1 = ((c1 & 7) ^ (r1 & 7)) * 8;
  const int kr0 = ((r0 >> 4) & 1) * 32 + ((r0 >> 2) & 3) * 8 + (r0 >> 5) * 4 + (r0 & 3);
  const int kr1 = ((r1 >> 4) & 1) * 32 + ((r1 >> 2) & 3) * 8 + (r1 >> 5) * 4 + (r1 & 3);

  bf16x8 qf[2][2];
#pragma unroll
  for (int qs = 0; qs < 2; ++qs)
#pragma unroll
    for (int dc = 0; dc < 2; ++dc)
      qf[qs][dc] = *(const bf16x8*)(qbase + (wv * 32 + qs * 16 + lm) * HD_ + dc * 32 + q4 * 8);

  const bf16x8 ones = {(__bf16)1.f, (__bf16)1.f, (__bf16)1.f, (__bf16)1.f,
                       (__bf16)1.f, (__bf16)1.f, (__bf16)1.f, (__bf16)1.f};

  // fragment base offsets (d-chunk 0 / 1); kb/db contribute imm kb*1024/db*1024
  const int base0 = lm * 64 + ((q4 ^ (lm & 7)) * 8);
  const int base1 = lm * 64 + (((4 + q4) ^ (lm & 7)) * 8);

  f32x4 oacc[2][4] = {};
  f32x4 liacc[2] = {};

  {
    g2l16(kbase + kr0 * HD_ + s0, Ks[0] + c0 * 8);
    g2l16(kbase + kr1 * HD_ + s1, Ks[0] + c1 * 8);
    g2l16(vbase + r0 * S_ + s0, Vs[0] + c0 * 8);
    g2l16(vbase + r1 * S_ + s1, Vs[0] + c1 * 8);
  }

  for (int t = 0; t < 32; ++t) {
    const int pb = t & 1;
    __syncthreads();
    if (t < 31) {
      const u16* kt = kbase + (size_t)(t + 1) * 64 * HD_;
      const u16* vt = vbase + (t + 1) * 64;
      g2l16(kt + kr0 * HD_ + s0, Ks[1 - pb] + c0 * 8);
      g2l16(kt + kr1 * HD_ + s1, Ks[1 - pb] + c1 * 8);
      g2l16(vt + r0 * S_ + s0, Vs[1 - pb] + c0 * 8);
      g2l16(vt + r1 * S_ + s1, Vs[1 - pb] + c1 * 8);
    }
    const u16* Kp = Ks[pb];
    const u16* Vp = Vs[pb];

#pragma unroll
    for (int ck = 0; ck < 2; ++ck) {
      bf16x8 ka0 = *(const bf16x8*)(Kp + ck * 1024 + base0);
      bf16x8 ka1 = *(const bf16x8*)(Kp + ck * 1024 + base1);
      bf16x8 kb0 = *(const bf16x8*)(Kp + (ck + 2) * 1024 + base0);
      bf16x8 kb1 = *(const bf16x8*)(Kp + (ck + 2) * 1024 + base1);
      bf16x8 pf[2];
#pragma unroll
      for (int qs = 0; qs < 2; ++qs) {
        f32x4 sa = {}, sb = {};
        sa = __builtin_amdgcn_mfma_f32_16x16x32_bf16(ka0, qf[qs][0], sa, 0, 0, 0);
        sa = __builtin_amdgcn_mfma_f32_16x16x32_bf16(ka1, qf[qs][1], sa, 0, 0, 0);
        sb = __builtin_amdgcn_mfma_f32_16x16x32_bf16(kb0, qf[qs][0], sb, 0, 0, 0);
        sb = __builtin_amdgcn_mfma_f32_16x16x32_bf16(kb1, qf[qs][1], sb, 0, 0, 0);
        f32x4 pa, pb2;
#pragma unroll
        for (int r = 0; r < 4; ++r) { pa[r] = EXP2F(sa[r]); pb2[r] = EXP2F(sb[r]); }
        bf16x4 la = __builtin_convertvector(pa, bf16x4);
        bf16x4 lb = __builtin_convertvector(pb2, bf16x4);
        pf[qs] = __builtin_shufflevector(la, lb, 0, 1, 2, 3, 4, 5, 6, 7);
      }
      const int vsel = ck ? base1 : base0;
      __builtin_amdgcn_s_setprio(1);
#pragma unroll
      for (int qs = 0; qs < 2; ++qs)
        liacc[qs] = __builtin_amdgcn_mfma_f32_16x16x32_bf16(pf[qs], ones, liacc[qs], 0, 0, 0);
#pragma unroll
      for (int db = 0; db < 4; ++db) {
        bf16x8 vf = *(const bf16x8*)(Vp + db * 1024 + vsel);
#pragma unroll
        for (int qs = 0; qs < 2; ++qs)
          oacc[qs][db] = __builtin_amdgcn_mfma_f32_16x16x32_bf16(pf[qs], vf, oacc[qs][db], 0, 0, 0);
      }
      __builtin_amdgcn_s_setprio(0);
    }
  }

  // ---- normalize + store (wave owns its 32 q-rows; li is in-lane) ----
#pragma unroll
  for (int qs = 0; qs < 2; ++qs) {
    float rin[4];
#pragma unroll
    for (int r = 0; r < 4; ++r) rin[r] = 1.f / liacc[qs][r];
#pragma unroll
    for (int db = 0; db < 4; ++db) {
      f32x4 vv;
#pragma unroll
      for (int r = 0; r < 4; ++r) vv[r] = oacc[qs][db][r] * rin[r];
      bf16x4 ov = __builtin_convertvector(vv, bf16x4);
      ushort4 us = *(ushort4*)&ov;
      int m0 = wv * 32 + qs * 16 + q4 * 4;
      zbase[(m0 + 0) * HD_ + db * 16 + lm] = us.x;
      zbase[(m0 + 1) * HD_ + db * 16 + lm] = us.y;
      zbase[(m0 + 2) * HD_ + db * 16 + lm] = us.z;
      zbase[(m0 + 3) * HD_ + db * 16 + lm] = us.w;
    }
  }
}

// ---------------- host ----------------
extern "C" void kernel_launch(void* const* d_in, const int* in_sizes, int n_in,
                              void* d_out, int out_size, void* d_ws, size_t ws_size,
                              hipStream_t stream) {
  const float* x  = (const float*)d_in[0];
  const float* Wq = (const float*)d_in[1];
  const float* bq = (const float*)d_in[2];
  const float* Wk = (const float*)d_in[3];
  const float* bk = (const float*)d_in[4];
  const float* Wv = (const float*)d_in[5];
  const float* bv = (const float*)d_in[6];
  const float* Wo = (const float*)d_in[7];
  const float* bo = (const float*)d_in[8];
  float* out = (float*)d_out;

  char* w = (char*)d_ws;
  u16*   xb    = (u16*)w;   w += (size_t)M_ * E_ * 2;
  u16*   wqkvT = (u16*)w;   w += (size_t)3 * HD_ * E_ * 2;
  u16*   woT   = (u16*)w;   w += (size_t)E_ * HD_ * 2;
  u16*   qB    = (u16*)w;   w += (size_t)M_ * HD_ * 2;
  u16*   kB    = (u16*)w;   w += (size_t)M_ * HD_ * 2;
  u16*   vT    = (u16*)w;   w += (size_t)M_ * HD_ * 2;     // V^T written by gemm0
  u16*   zB    = (u16*)w;   w += (size_t)M_ * HD_ * 2;

  prep_kernel<<<dim3(9216), 256, 0, stream>>>(x, Wq, Wk, Wv, Wo, xb, wqkvT, woT);
  gemm_qkv_kernel<<<dim3(1536), 256, 0, stream>>>(xb, wqkvT, bq, bk, bv,
                                                  qB, kB, vT);
  flash_kernel<<<dim3(1024), 256, 0, stream>>>(qB, kB, vT, zB);
  gemm_o_kernel<<<dim3(1024), 256, 0, stream>>>(zB, woT, bo, out);
}

// Round 13
// 261.974 us; speedup vs baseline: 1.0760x; 1.0319x over previous
//
#include <hip/hip_runtime.h>
#include <hip/hip_bf16.h>

#define B_  4
#define S_  2048
#define E_  1024
#define H_  16
#define DH_ 64
#define M_  (B_*S_)    // 8192 rows
#define HD_ (H_*DH_)   // 1024

typedef unsigned short u16;
typedef __attribute__((ext_vector_type(8))) __bf16 bf16x8;
typedef __attribute__((ext_vector_type(4))) __bf16 bf16x4;
typedef __attribute__((ext_vector_type(4))) float  f32x4;

#if __has_builtin(__builtin_amdgcn_exp2f)
#define EXP2F __builtin_amdgcn_exp2f
#else
#define EXP2F __builtin_exp2f
#endif

// softmax scale folded into Q at QKV epilogue: 1/sqrt(64) * log2(e)
#define QSCALE 0.18033688011112042f

// ---- async global->LDS, 16B per lane ----
__device__ __forceinline__ void g2l16(const void* g, void* l) {
  __builtin_amdgcn_global_load_lds(
      (const __attribute__((address_space(1))) void*)g,
      (__attribute__((address_space(3))) void*)l, 16, 0, 0);
}

// RNE float -> bf16 bits (scalar path, used in prep only)
__device__ __forceinline__ u16 f2bf(float f) {
  union { float f; unsigned u; } v; v.f = f;
  unsigned r = v.u + 0x7FFFu + ((v.u >> 16) & 1u);
  return (u16)(r >> 16);
}

// ---------------- fused prep: cvt_x | pack_wqkv | pack_wo ----------------
// R13: branches 2/3 vectorized (float4 loads, ushort4 stores; tile pitch 68
// for 8B alignment). Branch 1 and consumers unchanged.
__global__ __launch_bounds__(256) void prep_kernel(
    const float* __restrict__ x, const float* __restrict__ Wq,
    const float* __restrict__ Wk, const float* __restrict__ Wv,
    const float* __restrict__ Wo,
    u16* __restrict__ xb, u16* __restrict__ wqkvT, u16* __restrict__ woT) {
  __shared__ u16 tile[64][68];
  const int blk = blockIdx.x, tid = threadIdx.x;
  if (blk < 8192) {
    int i = blk * 256 + tid;
    float4 v = ((const float4*)x)[i];
    ushort4 o;
    o.x = f2bf(v.x); o.y = f2bf(v.y); o.z = f2bf(v.z); o.w = f2bf(v.w);
    ((ushort4*)xb)[i] = o;
  } else if (blk < 8960) {
    int b2 = blk - 8192;
    int p = b2 >> 8, h = (b2 >> 4) & 15, e0 = (b2 & 15) * 64;
    const float* src = (p == 0 ? Wq : (p == 1 ? Wk : Wv)) + h * (E_ * DH_);
#pragma unroll
    for (int r = 0; r < 4; ++r) {
      int idx = r * 256 + tid;
      int el = idx >> 4, d4 = (idx & 15) * 4;
      float4 v = *(const float4*)(src + (e0 + el) * DH_ + d4);
      ushort4 o;
      o.x = f2bf(v.x); o.y = f2bf(v.y); o.z = f2bf(v.z); o.w = f2bf(v.w);
      *(ushort4*)&tile[el][d4] = o;
    }
    __syncthreads();
    u16* dst = wqkvT + (p * HD_ + h * DH_) * E_;
#pragma unroll
    for (int r = 0; r < 4; ++r) {
      int idx = r * 256 + tid;
      int d = idx >> 4, el4 = (idx & 15) * 4;
      ushort4 o;
      o.x = tile[el4 + 0][d]; o.y = tile[el4 + 1][d];
      o.z = tile[el4 + 2][d]; o.w = tile[el4 + 3][d];
      *(ushort4*)(dst + d * E_ + e0 + el4) = o;
    }
  } else {
    int b3 = blk - 8960;
    int c0 = (b3 >> 4) * 64, e0 = (b3 & 15) * 64;
#pragma unroll
    for (int r = 0; r < 4; ++r) {
      int idx = r * 256 + tid;
      int cl = idx >> 4, el4 = (idx & 15) * 4;
      float4 v = *(const float4*)(Wo + (c0 + cl) * E_ + e0 + el4);
      ushort4 o;
      o.x = f2bf(v.x); o.y = f2bf(v.y); o.z = f2bf(v.z); o.w = f2bf(v.w);
      *(ushort4*)&tile[cl][el4] = o;
    }
    __syncthreads();
#pragma unroll
    for (int r = 0; r < 4; ++r) {
      int idx = r * 256 + tid;
      int er = idx >> 4, cl4 = (idx & 15) * 4;
      ushort4 o;
      o.x = tile[cl4 + 0][er]; o.y = tile[cl4 + 1][er];
      o.z = tile[cl4 + 2][er]; o.w = tile[cl4 + 3][er];
      *(ushort4*)(woT + (e0 + er) * HD_ + c0 + cl4) = o;
    }
  }
}

// ---------------- GEMM (QKV): C[M][3072] = xb * wqkvT^T, 128x128 tiles ----
// QKV epilogue — bias, bf16, then LDS round-trip to emit 16B coalesced
// stores. Q/K in [m][cc] orientation; V written DIRECTLY as V^T [b,h,d,s].
// SCHEDULE AND DISPATCH ORDER ARE FROZEN (4 failed restructures):
//  R3:  2-phase/counted-vmcnt 128x256 graft  -> neutral
//  R11: 4-quadrant-phase 256^2 "template port" -> 82 us, MfmaUtil 24%
//  R12: "XCD-stripe" swizzle -> 77.7 us, FETCH 59.7->199.8 MB — each XCD
//       swept all M per N-stripe, streaming 16 MB A through 4 MB L2 x3.
//       The DEFAULT 2D (24,64) round-robin is already the good order.
__global__ __launch_bounds__(256) void gemm_qkv_kernel(
    const u16* __restrict__ A, const u16* __restrict__ Bt,
    const float* __restrict__ b0, const float* __restrict__ b1,
    const float* __restrict__ b2,
    u16* __restrict__ oQ, u16* __restrict__ oK, u16* __restrict__ oV) {
  constexpr int K = 1024;
  __shared__ __align__(16) u16 smem[2 * 128 * 64];   // As | Bs; reused as C-tile
  u16* As = smem;
  u16* Bs = smem + 128 * 64;
  const int tid = threadIdx.x;
  const int lane = tid & 63, wv = tid >> 6;
  const int wm = (wv >> 1) * 64, wn = (wv & 1) * 64;
  const int q4 = lane >> 4, lm = lane & 15;
  const int tileM = blockIdx.y * 128, tileN = blockIdx.x * 128;

  const u16* gA[4]; const u16* gB[4]; u16* lA[4]; u16* lB[4];
#pragma unroll
  for (int rr = 0; rr < 4; ++rr) {
    int c = rr * 256 + tid;
    int r = c >> 3, sw = ((c & 7) ^ (r & 7)) * 8;
    gA[rr] = A + (size_t)(tileM + r) * K + sw;
    gB[rr] = Bt + (size_t)(tileN + r) * K + sw;
    lA[rr] = As + c * 8;
    lB[rr] = Bs + c * 8;
  }

  f32x4 acc[4][4] = {};

  int aoff[2][4], boff[2][4];
#pragma unroll
  for (int ks = 0; ks < 2; ++ks) {
#pragma unroll
    for (int i = 0; i < 4; ++i) {
      int ra = wm + i * 16 + lm;
      aoff[ks][i] = ra * 64 + (((ks * 4 + q4) ^ (ra & 7)) * 8);
      int rb = wn + i * 16 + lm;
      boff[ks][i] = rb * 64 + (((ks * 4 + q4) ^ (rb & 7)) * 8);
    }
  }

  for (int k0 = 0; k0 < K; k0 += 64) {
#pragma unroll
    for (int rr = 0; rr < 4; ++rr) {
      g2l16(gA[rr] + k0, lA[rr]);
      g2l16(gB[rr] + k0, lB[rr]);
    }
    __syncthreads();
#pragma unroll
    for (int ks = 0; ks < 2; ++ks) {
      bf16x8 af[4], bf[4];
#pragma unroll
      for (int i = 0; i < 4; ++i) af[i] = *(const bf16x8*)(As + aoff[ks][i]);
#pragma unroll
      for (int j = 0; j < 4; ++j) bf[j] = *(const bf16x8*)(Bs + boff[ks][j]);
#pragma unroll
      for (int i = 0; i < 4; ++i)
#pragma unroll
        for (int j = 0; j < 4; ++j)
          acc[i][j] = __builtin_amdgcn_mfma_f32_16x16x32_bf16(af[i], bf[j], acc[i][j], 0, 0, 0);
    }
    __syncthreads();
  }

  // ---- LDS round-trip epilogue (after final barrier, smem is free) ----
  u16* TT = smem;                        // 128 x 128 bf16, swizzled
  const int ccb = tileN & 1023;
  const int proj = tileN >> 10;          // uniform per block
  const float scl = (proj == 0 ? QSCALE : 1.0f);
  const float* bp = (proj == 0 ? b0 : (proj == 1 ? b1 : b2));
#pragma unroll
  for (int j = 0; j < 4; ++j) {
    int ncl = wn + j * 16 + lm;
    float bs = bp[ccb + ncl];
#pragma unroll
    for (int i = 0; i < 4; ++i) {
      int m0 = wm + i * 16 + q4 * 4;
      f32x4 vv;
#pragma unroll
      for (int r = 0; r < 4; ++r) vv[r] = (acc[i][j][r] + bs) * scl;
      bf16x4 ov = __builtin_convertvector(vv, bf16x4);
      if (proj < 2) {
        // orientation A: element (ml, ccl) at ml*128 + (ccl ^ 8*(ml&15))
        ushort4 us = *(ushort4*)&ov;
        TT[(m0 + 0) * 128 + (ncl ^ (8 * ((m0 + 0) & 15)))] = us.x;
        TT[(m0 + 1) * 128 + (ncl ^ (8 * ((m0 + 1) & 15)))] = us.y;
        TT[(m0 + 2) * 128 + (ncl ^ (8 * ((m0 + 2) & 15)))] = us.z;
        TT[(m0 + 3) * 128 + (ncl ^ (8 * ((m0 + 3) & 15)))] = us.w;
      } else {
        // orientation B: element (ccl, ml) at ccl*128 + (ml ^ 8*(ccl&15))
        *(bf16x4*)(TT + ncl * 128 + (m0 ^ (8 * (ncl & 15)))) = ov;  // b64
      }
    }
  }
  __syncthreads();
  if (proj < 2) {
    u16* optr = (proj == 0 ? oQ : oK);
#pragma unroll
    for (int rr = 0; rr < 8; ++rr) {
      int seg = rr * 256 + tid;
      int ml = seg >> 4, sc = (seg & 15) * 8;
      uint4 val = *(const uint4*)(TT + ml * 128 + (sc ^ (8 * (ml & 15))));
      *(uint4*)(optr + (size_t)(tileM + ml) * 1024 + ccb + sc) = val;
    }
  } else {
    const int bb = tileM >> 11, s0 = tileM & 2047;
#pragma unroll
    for (int rr = 0; rr < 8; ++rr) {
      int seg = rr * 256 + tid;
      int ccl = seg >> 4, sc = (seg & 15) * 8;
      int cc = ccb + ccl;
      int hh = cc >> 6, dd = cc & 63;
      uint4 val = *(const uint4*)(TT + ccl * 128 + (sc ^ (8 * (ccl & 15))));
      *(uint4*)(oV + ((size_t)(bb * 16 + hh) * 64 + dd) * 2048 + s0 + sc) = val;
    }
  }
}

// ---------------- GEMM (out-proj): C[M][1024] = zB * woT^T, 64x128 tiles ----
// R8 measured: this 4-blocks/CU config beat the old 128x128 2-blocks/CU by
// ~5 us total. Keep.
__global__ __launch_bounds__(256) void gemm_o_kernel(
    const u16* __restrict__ A, const u16* __restrict__ Bt,
    const float* __restrict__ bo, float* __restrict__ oF) {
  constexpr int K = 1024;
  __shared__ __align__(16) u16 smem[(64 + 128) * 64];   // As(64x64) | Bs(128x64)
  u16* As = smem;
  u16* Bs = smem + 64 * 64;
  const int tid = threadIdx.x;
  const int lane = tid & 63, wv = tid >> 6;
  const int wm = (wv >> 1) * 32, wn = (wv & 1) * 64;
  const int q4 = lane >> 4, lm = lane & 15;

  // XCD-bijective swizzle over 1024 blocks (1024 % 8 == 0)
  const int bid = blockIdx.x;
  const int wg = (bid & 7) * 128 + (bid >> 3);
  const int tileN = (wg & 7) * 128, tileM = (wg >> 3) * 64;

  const u16* gA[2]; const u16* gB[4]; u16* lA[2]; u16* lB[4];
#pragma unroll
  for (int rr = 0; rr < 2; ++rr) {
    int c = rr * 256 + tid;
    int r = c >> 3, sw = ((c & 7) ^ (r & 7)) * 8;
    gA[rr] = A + (size_t)(tileM + r) * K + sw;
    lA[rr] = As + c * 8;
  }
#pragma unroll
  for (int rr = 0; rr < 4; ++rr) {
    int c = rr * 256 + tid;
    int r = c >> 3, sw = ((c & 7) ^ (r & 7)) * 8;
    gB[rr] = Bt + (size_t)(tileN + r) * K + sw;
    lB[rr] = Bs + c * 8;
  }

  f32x4 acc[2][4] = {};

  int aoff[2][2], boff[2][4];
#pragma unroll
  for (int ks = 0; ks < 2; ++ks) {
#pragma unroll
    for (int i = 0; i < 2; ++i) {
      int ra = wm + i * 16 + lm;
      aoff[ks][i] = ra * 64 + (((ks * 4 + q4) ^ (ra & 7)) * 8);
    }
#pragma unroll
    for (int j = 0; j < 4; ++j) {
      int rb = wn + j * 16 + lm;
      boff[ks][j] = rb * 64 + (((ks * 4 + q4) ^ (rb & 7)) * 8);
    }
  }

  for (int k0 = 0; k0 < K; k0 += 64) {
#pragma unroll
    for (int rr = 0; rr < 2; ++rr) g2l16(gA[rr] + k0, lA[rr]);
#pragma unroll
    for (int rr = 0; rr < 4; ++rr) g2l16(gB[rr] + k0, lB[rr]);
    __syncthreads();
#pragma unroll
    for (int ks = 0; ks < 2; ++ks) {
      bf16x8 af[2], bf[4];
#pragma unroll
      for (int i = 0; i < 2; ++i) af[i] = *(const bf16x8*)(As + aoff[ks][i]);
#pragma unroll
      for (int j = 0; j < 4; ++j) bf[j] = *(const bf16x8*)(Bs + boff[ks][j]);
#pragma unroll
      for (int i = 0; i < 2; ++i)
#pragma unroll
        for (int j = 0; j < 4; ++j)
          acc[i][j] = __builtin_amdgcn_mfma_f32_16x16x32_bf16(af[i], bf[j], acc[i][j], 0, 0, 0);
    }
    __syncthreads();
  }

#pragma unroll
  for (int j = 0; j < 4; ++j) {
    int n = tileN + wn + j * 16 + lm;
    float bs = bo[n];
#pragma unroll
    for (int i = 0; i < 2; ++i) {
      int m0 = tileM + wm + i * 16 + q4 * 4;
#pragma unroll
      for (int r = 0; r < 4; ++r) oF[(m0 + r) * HD_ + n] = acc[i][j][r] + bs;
    }
  }
}

// ---------------- flash attention — R4 proven config (do not touch) --------
// R4/R8 measured: 74-76.5 us, VGPR 56, occupancy 34%. R5's QK-one-tile-ahead
// pipeline REGRESSED to 92 us (MFMA-busy unchanged, +15 us stall) — do not
// re-pipeline this loop at source level.
// KEY PERMUTATION: K rows staged at LDS slot s = kb*16+q4*4+r hold logical
// key kperm(s) = (kb&1)*32 + q4*8 + (kb>>1)*4 + r. The S^T-MFMA C-layout
// output IS the PV A-fragment layout per-lane; V keeps sequential key order.
// P never touches LDS.
// REGISTER RULE: keep launch_bounds (256,2); tighter -> spill storm.
__global__ __launch_bounds__(256, 2) void flash_kernel(
    const u16* __restrict__ Q, const u16* __restrict__ Kb,
    const u16* __restrict__ Vt, u16* __restrict__ Z) {
  __shared__ __align__(16) u16 Ks[2][64 * 64];   // [slot][d] swizzled, key-permuted
  __shared__ __align__(16) u16 Vs[2][64 * 64];   // [d][key] swizzled, sequential
  const int tid = threadIdx.x, lane = tid & 63, wv = tid >> 6;
  const int q4 = lane >> 4, lm = lane & 15;

  const int bid = blockIdx.x;
  const int bh = bid >> 4, qt = bid & 15;        // 16 consecutive blocks share (b,h) K/V
  const int b = bh >> 4, h = bh & 15;

  const u16* qbase = Q + ((size_t)(b * S_ + qt * 128)) * HD_ + h * DH_;
  const u16* kbase = Kb + (size_t)b * S_ * HD_ + h * DH_;
  const u16* vbase = Vt + ((size_t)(b * H_ + h)) * DH_ * S_;
  u16* zbase = Z + ((size_t)(b * S_ + qt * 128)) * HD_ + h * DH_;

  const int c0 = tid,       r0 = c0 >> 3, s0 = ((c0 & 7) ^ (r0 & 7)) * 8;
  const int c1 = tid + 256, r1 = c1 >> 3, s1 = ((c1 & 7) ^ (r1 & 7)) * 8;
  const int kr0 = ((r0 >> 4) & 1) * 32 + ((r0 >> 2) & 3) * 8 + (r0 >> 5) * 4 + (r0 & 3);
  const int kr1 = ((r1 >> 4) & 1) * 32 + ((r1 >> 2) & 3) * 8 + (r1 >> 5) * 4 + (r1 & 3);

  bf16x8 qf[2][2];
#pragma unroll
  for (int qs = 0; qs < 2; ++qs)
#pragma unroll
    for (int dc = 0; dc < 2; ++dc)
      qf[qs][dc] = *(const bf16x8*)(qbase + (wv * 32 + qs * 16 + lm) * HD_ + dc * 32 + q4 * 8);

  const bf16x8 ones = {(__bf16)1.f, (__bf16)1.f, (__bf16)1.f, (__bf16)1.f,
                       (__bf16)1.f, (__bf16)1.f, (__bf16)1.f, (__bf16)1.f};

  // fragment base offsets (d-chunk 0 / 1); kb/db contribute imm kb*1024/db*1024
  const int base0 = lm * 64 + ((q4 ^ (lm & 7)) * 8);
  const int base1 = lm * 64 + (((4 + q4) ^ (lm & 7)) * 8);

  f32x4 oacc[2][4] = {};
  f32x4 liacc[2] = {};

  {
    g2l16(kbase + kr0 * HD_ + s0, Ks[0] + c0 * 8);
    g2l16(kbase + kr1 * HD_ + s1, Ks[0] + c1 * 8);
    g2l16(vbase + r0 * S_ + s0, Vs[0] + c0 * 8);
    g2l16(vbase + r1 * S_ + s1, Vs[0] + c1 * 8);
  }

  for (int t = 0; t < 32; ++t) {
    const int pb = t & 1;
    __syncthreads();
    if (t < 31) {
      const u16* kt = kbase + (size_t)(t + 1) * 64 * HD_;
      const u16* vt = vbase + (t + 1) * 64;
      g2l16(kt + kr0 * HD_ + s0, Ks[1 - pb] + c0 * 8);
      g2l16(kt + kr1 * HD_ + s1, Ks[1 - pb] + c1 * 8);
      g2l16(vt + r0 * S_ + s0, Vs[1 - pb] + c0 * 8);
      g2l16(vt + r1 * S_ + s1, Vs[1 - pb] + c1 * 8);
    }
    const u16* Kp = Ks[pb];
    const u16* Vp = Vs[pb];

#pragma unroll
    for (int ck = 0; ck < 2; ++ck) {
      bf16x8 ka0 = *(const bf16x8*)(Kp + ck * 1024 + base0);
      bf16x8 ka1 = *(const bf16x8*)(Kp + ck * 1024 + base1);
      bf16x8 kb0 = *(const bf16x8*)(Kp + (ck + 2) * 1024 + base0);
      bf16x8 kb1 = *(const bf16x8*)(Kp + (ck + 2) * 1024 + base1);
      bf16x8 pf[2];
#pragma unroll
      for (int qs = 0; qs < 2; ++qs) {
        f32x4 sa = {}, sb = {};
        sa = __builtin_amdgcn_mfma_f32_16x16x32_bf16(ka0, qf[qs][0], sa, 0, 0, 0);
        sa = __builtin_amdgcn_mfma_f32_16x16x32_bf16(ka1, qf[qs][1], sa, 0, 0, 0);
        sb = __builtin_amdgcn_mfma_f32_16x16x32_bf16(kb0, qf[qs][0], sb, 0, 0, 0);
        sb = __builtin_amdgcn_mfma_f32_16x16x32_bf16(kb1, qf[qs][1], sb, 0, 0, 0);
        f32x4 pa, pb2;
#pragma unroll
        for (int r = 0; r < 4; ++r) { pa[r] = EXP2F(sa[r]); pb2[r] = EXP2F(sb[r]); }
        bf16x4 la = __builtin_convertvector(pa, bf16x4);
        bf16x4 lb = __builtin_convertvector(pb2, bf16x4);
        pf[qs] = __builtin_shufflevector(la, lb, 0, 1, 2, 3, 4, 5, 6, 7);
      }
      const int vsel = ck ? base1 : base0;
      __builtin_amdgcn_s_setprio(1);
#pragma unroll
      for (int qs = 0; qs < 2; ++qs)
        liacc[qs] = __builtin_amdgcn_mfma_f32_16x16x32_bf16(pf[qs], ones, liacc[qs], 0, 0, 0);
#pragma unroll
      for (int db = 0; db < 4; ++db) {
        bf16x8 vf = *(const bf16x8*)(Vp + db * 1024 + vsel);
#pragma unroll
        for (int qs = 0; qs < 2; ++qs)
          oacc[qs][db] = __builtin_amdgcn_mfma_f32_16x16x32_bf16(pf[qs], vf, oacc[qs][db], 0, 0, 0);
      }
      __builtin_amdgcn_s_setprio(0);
    }
  }

  // ---- normalize + store (wave owns its 32 q-rows; li is in-lane) ----
#pragma unroll
  for (int qs = 0; qs < 2; ++qs) {
    float rin[4];
#pragma unroll
    for (int r = 0; r < 4; ++r) rin[r] = 1.f / liacc[qs][r];
#pragma unroll
    for (int db = 0; db < 4; ++db) {
      f32x4 vv;
#pragma unroll
      for (int r = 0; r < 4; ++r) vv[r] = oacc[qs][db][r] * rin[r];
      bf16x4 ov = __builtin_convertvector(vv, bf16x4);
      ushort4 us = *(ushort4*)&ov;
      int m0 = wv * 32 + qs * 16 + q4 * 4;
      zbase[(m0 + 0) * HD_ + db * 16 + lm] = us.x;
      zbase[(m0 + 1) * HD_ + db * 16 + lm] = us.y;
      zbase[(m0 + 2) * HD_ + db * 16 + lm] = us.z;
      zbase[(m0 + 3) * HD_ + db * 16 + lm] = us.w;
    }
  }
}

// ---------------- host ----------------
extern "C" void kernel_launch(void* const* d_in, const int* in_sizes, int n_in,
                              void* d_out, int out_size, void* d_ws, size_t ws_size,
                              hipStream_t stream) {
  const float* x  = (const float*)d_in[0];
  const float* Wq = (const float*)d_in[1];
  const float* bq = (const float*)d_in[2];
  const float* Wk = (const float*)d_in[3];
  const float* bk = (const float*)d_in[4];
  const float* Wv = (const float*)d_in[5];
  const float* bv = (const float*)d_in[6];
  const float* Wo = (const float*)d_in[7];
  const float* bo = (const float*)d_in[8];
  float* out = (float*)d_out;

  char* w = (char*)d_ws;
  u16*   xb    = (u16*)w;   w += (size_t)M_ * E_ * 2;
  u16*   wqkvT = (u16*)w;   w += (size_t)3 * HD_ * E_ * 2;
  u16*   woT   = (u16*)w;   w += (size_t)E_ * HD_ * 2;
  u16*   qB    = (u16*)w;   w += (size_t)M_ * HD_ * 2;
  u16*   kB    = (u16*)w;   w += (size_t)M_ * HD_ * 2;
  u16*   vT    = (u16*)w;   w += (size_t)M_ * HD_ * 2;     // V^T written by gemm0
  u16*   zB    = (u16*)w;   w += (size_t)M_ * HD_ * 2;

  prep_kernel<<<dim3(9216), 256, 0, stream>>>(x, Wq, Wk, Wv, Wo, xb, wqkvT, woT);
  gemm_qkv_kernel<<<dim3(24, 64), 256, 0, stream>>>(xb, wqkvT, bq, bk, bv,
                                                    qB, kB, vT);
  flash_kernel<<<dim3(1024), 256, 0, stream>>>(qB, kB, vT, zB);
  gemm_o_kernel<<<dim3(1024), 256, 0, stream>>>(zB, woT, bo, out);
}